// Round 14
// baseline (193.000 us; speedup 1.0000x reference)
//
#include <hip/hip_runtime.h>
#include <hip/hip_bf16.h>
#include <cstdint>
#include <cstddef>

// MHA fused pipeline, bf16 MFMA everywhere, fp32 accumulate.
// B=2 N=2048 E=1024 H=16 D=64; M = B*N = 4096; BH = 32.
// R1: attn LDS XOR-swizzle (verified: SQ_LDS_BANK_CONFLICT=0).
// R2: swapped QK^T -> lane-local softmax (122 -> 76 us).
// R4/R5: K/V dbuf prefetch, exp2 softmax, defer-max, XCD swizzles (-> 67 us).
// R6: GEMMs BK=64 + T2 swizzle; attn setprio REGRESSED (-> 70.6).
// R7/R8: revert setprio, cvt_pk casts, tree reductions (-> 63.3 us).
// R9/R10: ones-MFMA denominator + launch diet (attn 64.1; total 192).
// R11: K16 in-register PV REGRESSED (68.4). R12: 3-buf counted vmcnt (-> 59.7).
// R13: KVBLK=128 REGRESSED (62.7; V-layout conflicts 3x). Total noise ~±3us.
// R14: revert attn to R12 exactly; merge both weight transposes into one launch.

typedef __attribute__((ext_vector_type(8))) short short8;   // 8 bf16 (4 VGPR)
typedef __attribute__((ext_vector_type(4))) short short4v;
typedef __attribute__((ext_vector_type(4))) float f32x4;

#define MFMA16(a, b, c) __builtin_amdgcn_mfma_f32_16x16x32_bf16((a), (b), (c), 0, 0, 0)
#define EXP2F(x) __builtin_amdgcn_exp2f(x)

__device__ __forceinline__ float b2f(short s) {
  union { unsigned u; float f; } x; x.u = ((unsigned)(unsigned short)s) << 16; return x.f;
}
__device__ __forceinline__ short f2b(float f) {  // native RNE cast (cvt_pk-fusable)
  union { __hip_bfloat16 h; short s; } u; u.h = __float2bfloat16(f); return u.s;
}
__device__ __forceinline__ void async_lds16(const void* g, void* l) {
  __builtin_amdgcn_global_load_lds(
      (const __attribute__((address_space(1))) void*)g,
      (__attribute__((address_space(3))) void*)l, 16, 0, 0);
}

// ---------------- cast x (fp32 -> bf16), vectorized, grid-stride ----------------
__global__ __launch_bounds__(256) void cast_f32_bf16(const float* __restrict__ in,
                                                     short* __restrict__ out, int n4) {
  for (int idx = blockIdx.x * 256 + threadIdx.x; idx < n4; idx += 1024 * 256) {
    f32x4 v = ((const f32x4*)in)[idx];
    short4v o;
    #pragma unroll
    for (int e = 0; e < 4; ++e) o[e] = f2b(v[e]);
    ((short4v*)out)[idx] = o;
  }
}

// ---- merged transpose+cast for BOTH weights: [1024][C] f32 -> [C][1024] bf16 ----
// blocks 0..767: wqkv (C=3072, 48x16 tiles); blocks 768..1023: wproj (C=1024, 16x16).
__global__ __launch_bounds__(256) void transpose_cast_w(const float* __restrict__ wqkv,
                                                        short* __restrict__ wqkvT,
                                                        const float* __restrict__ wproj,
                                                        short* __restrict__ wprojT) {
  __shared__ float tile[64][65];
  int b = blockIdx.x;
  const float* in;
  short* out;
  int C, bx, by;
  if (b < 768) { in = wqkv;  out = wqkvT;  C = 3072; bx = b % 48; by = b / 48; }
  else { b -= 768; in = wproj; out = wprojT; C = 1024; bx = b % 16; by = b / 16; }
  const int R = 1024;
  int c0 = bx * 64, r0 = by * 64;
  int tx = threadIdx.x & 63, ty = threadIdx.x >> 6;  // 64 x 4
  #pragma unroll
  for (int i = ty; i < 64; i += 4)
    tile[i][tx] = in[(size_t)(r0 + i) * C + c0 + tx];
  __syncthreads();
  #pragma unroll
  for (int i = ty; i < 64; i += 4)
    out[(size_t)(c0 + i) * R + r0 + tx] = f2b(tile[tx][i]);
}

// ---------------- GEMM1: qkv = xb @ wqkvT^T + bias, scatter to Q/K/Vt ----------------
// 128x128 tile, BK=64, 1D grid 768, chunked XCD swizzle. LDS [128][64] with
// T2 XOR swizzle: 16B-block idx ^= (row&7); linear LDS dest + pre-swz source.
__global__ __launch_bounds__(256, 3) void gemm_qkv(const short* __restrict__ xb,
                                                   const short* __restrict__ wT,
                                                   const float* __restrict__ bias,
                                                   short* __restrict__ Qb,
                                                   short* __restrict__ Kb,
                                                   short* __restrict__ Vt) {
  __shared__ short lds_a[128 * 64];
  __shared__ short lds_b[128 * 64];
  const int tid = threadIdx.x, wid = tid >> 6, lane = tid & 63;
  const int lg = lane >> 4, lr = lane & 15;
  const int lin = blockIdx.x;
  const int swz = (lin & 7) * 96 + (lin >> 3);   // XCD k owns swz [k*96, (k+1)*96)
  const int m0 = (swz & 31) * 128, n0 = (swz >> 5) * 128;
  const int wr = wid >> 1, wc = wid & 1;
  const int K = 1024;
  const int sm = lr & 7;                         // read-side swizzle mask

  f32x4 acc[4][4];
  #pragma unroll
  for (int i = 0; i < 4; ++i)
    #pragma unroll
    for (int j = 0; j < 4; ++j) acc[i][j] = (f32x4)0.0f;

  for (int k0 = 0; k0 < K; k0 += 64) {
    #pragma unroll
    for (int it = 0; it < 4; ++it) {
      int chunk = it * 256 + tid;
      int row = chunk >> 3, kc = ((chunk & 7) ^ (row & 7)) * 8;  // pre-swz source
      async_lds16(xb + (size_t)(m0 + row) * K + k0 + kc, lds_a + chunk * 8);
      async_lds16(wT + (size_t)(n0 + row) * K + k0 + kc, lds_b + chunk * 8);
    }
    __syncthreads();
    #pragma unroll
    for (int kk = 0; kk < 2; ++kk) {
      short8 af[4], bfr[4];
      #pragma unroll
      for (int i = 0; i < 4; ++i)
        af[i] = *(const short8*)&lds_a[(wr * 64 + i * 16 + lr) * 64 +
                                       (((kk * 4 + lg) ^ sm) * 8)];
      #pragma unroll
      for (int j = 0; j < 4; ++j)
        bfr[j] = *(const short8*)&lds_b[(wc * 64 + j * 16 + lr) * 64 +
                                        (((kk * 4 + lg) ^ sm) * 8)];
      #pragma unroll
      for (int i = 0; i < 4; ++i)
        #pragma unroll
        for (int j = 0; j < 4; ++j) acc[i][j] = MFMA16(af[i], bfr[j], acc[i][j]);
    }
    __syncthreads();
  }

  // epilogue: C/D layout col = lane&15, row = (lane>>4)*4 + reg
  #pragma unroll
  for (int i = 0; i < 4; ++i) {
    int gm = m0 + wr * 64 + i * 16 + lg * 4;  // rows gm..gm+3 (same b: gm%4==0)
    int bb = gm >> 11, n = gm & 2047;
    #pragma unroll
    for (int j = 0; j < 4; ++j) {
      int gc = n0 + wc * 64 + j * 16 + lr;
      float bv = bias[gc];
      int which = gc >> 10;            // uniform per block (n0 % 128 == 0)
      int h = (gc >> 6) & 15;
      int dd = gc & 63;
      size_t qkbase = ((size_t)((bb * 16 + h) * 2048 + n)) * 64 + dd;
      if (which == 2) {                // Vt: r contiguous along n -> pack 8B
        size_t vtbase = ((size_t)((bb * 16 + h) * 64 + dd)) * 2048 + n;
        short4v pv;
        #pragma unroll
        for (int r = 0; r < 4; ++r) pv[r] = f2b(acc[i][j][r] + bv);
        *(short4v*)&Vt[vtbase] = pv;
      } else {
        short* dst = (which == 0) ? Qb : Kb;
        #pragma unroll
        for (int r = 0; r < 4; ++r)
          dst[qkbase + (size_t)r * 64] = f2b(acc[i][j][r] + bv);
      }
    }
  }
}

// ---------------- flash attention (swapped-operand, 3-buf counted vmcnt) ----------------
// 1D grid 512, 512 threads / 8 waves; wave owns 16 q-rows (q = q0+lr).
// KV tile = 64, TRIPLE-buffered, prefetch depth 2, counted vmcnt(2) (T4):
//   prologue: stage t0,t1; vmcnt(2); barrier.
//   iter t:   stage t+2 -> buf[(t+2)%3]; compute buf[t%3]; vmcnt(2); barrier.
// Newest 2 loads stay in flight across the barrier (never a full drain).
// Scores in log2 domain; defer-max THR=8; denominator via ones-MFMA.
__global__ __launch_bounds__(512) void attn_fwd(const short* __restrict__ Qb,
                                                const short* __restrict__ Kb,
                                                const short* __restrict__ Vt,
                                                short* __restrict__ aob) {
  __shared__ short k_lds[3][64 * 64];
  __shared__ short v_lds[3][64 * 64];
  __shared__ short p_lds[8 * 16 * 64];
  const int tid = threadIdx.x, wid = tid >> 6, lane = tid & 63;
  const int lg = lane >> 4, lr = lane & 15;
  const int lin = blockIdx.x;
  const int swz = (lin & 7) * 64 + (lin >> 3);
  const int qt = swz & 15, bh = swz >> 4;   // XCD k owns bh [k*4, k*4+4)
  const int q0 = qt * 128 + wid * 16;
  const short* Qbh = Qb + (size_t)bh * 2048 * 64;
  const short* Kbh = Kb + (size_t)bh * 2048 * 64;
  const short* Vbh = Vt + (size_t)bh * 64 * 2048;
  const int rm = (lr >> 1) & 7;   // read-side swizzle mask (rows indexed by lr)

  // stage one KV tile (linear LDS dest + pre-swizzled global source)
  const int srow = tid >> 3;
  const int ssrc = ((tid & 7) ^ ((srow >> 1) & 7)) * 8;

  // loop-invariant p_lds write/read offsets
  int pw[4], pr[2];
  #pragma unroll
  for (int jt = 0; jt < 4; ++jt)
    pw[jt] = wid * 1024 + lr * 64 + (((jt * 2 + (lg >> 1)) ^ rm) * 8) + (lg & 1) * 4;
  #pragma unroll
  for (int kk = 0; kk < 2; ++kk)
    pr[kk] = wid * 1024 + lr * 64 + (((kk * 4 + lg) ^ rm) * 8);

  // all-ones bf16 fragment for the denominator MFMA
  short8 ones;
  #pragma unroll
  for (int e = 0; e < 8; ++e) ones[e] = (short)0x3F80;

  // Q fragments hoisted; fold scale 0.125 * log2(e) (exp2-domain scores)
  short8 qf[2];
  #pragma unroll
  for (int kk = 0; kk < 2; ++kk) {
    qf[kk] = *(const short8*)(Qbh + (size_t)(q0 + lr) * 64 + kk * 32 + lg * 8);
    #pragma unroll
    for (int e = 0; e < 8; ++e) qf[kk][e] = f2b(b2f(qf[kk][e]) * 0.1803368801f);
  }

  f32x4 o[4], o_l;
  #pragma unroll
  for (int dt = 0; dt < 4; ++dt) o[dt] = (f32x4)0.0f;
  o_l = (f32x4)0.0f;
  float m_ = -__builtin_inff();

  // prologue: stage tiles 0 and 1 (2 loads each per thread)
  async_lds16(Kbh + (size_t)srow * 64 + ssrc, &k_lds[0][tid * 8]);
  async_lds16(Vbh + (size_t)srow * 2048 + 0 + ssrc, &v_lds[0][tid * 8]);
  async_lds16(Kbh + (size_t)(64 + srow) * 64 + ssrc, &k_lds[1][tid * 8]);
  async_lds16(Vbh + (size_t)srow * 2048 + 64 + ssrc, &v_lds[1][tid * 8]);
  asm volatile("s_waitcnt vmcnt(2)" ::: "memory");   // tile 0 landed; tile 1 in flight
  __syncthreads();

  int cur = 0, nx2 = 2;   // buffer of tile t, buffer for tile t+2
  for (int t = 0; t < 32; ++t) {
    // issue tile t+2 into the slot freed at t-1 (depth-2 prefetch)
    if (t + 2 < 32) {
      int kvn = (t + 2) * 64;
      async_lds16(Kbh + (size_t)(kvn + srow) * 64 + ssrc, &k_lds[nx2][tid * 8]);
      async_lds16(Vbh + (size_t)srow * 2048 + kvn + ssrc, &v_lds[nx2][tid * 8]);
    }

    // S^T = K Q^T : s[jt][r] = S[q=lr][k=jt*16+lg*4+r], log2 domain
    f32x4 s[4];
    #pragma unroll
    for (int jt = 0; jt < 4; ++jt) s[jt] = (f32x4)0.0f;
    #pragma unroll
    for (int jt = 0; jt < 4; ++jt)
      #pragma unroll
      for (int kk = 0; kk < 2; ++kk) {
        short8 kf = *(const short8*)&k_lds[cur][(jt * 16 + lr) * 64 +
                                               (((kk * 4 + lg) ^ rm) * 8)];
        s[jt] = MFMA16(kf, qf[kk], s[jt]);
      }

    // pmax: depth-4 tree (max3-fusable)
    float mj[4];
    #pragma unroll
    for (int jt = 0; jt < 4; ++jt)
      mj[jt] = fmaxf(fmaxf(s[jt][0], s[jt][1]), fmaxf(s[jt][2], s[jt][3]));
    float pmax = fmaxf(fmaxf(mj[0], mj[1]), fmaxf(mj[2], mj[3]));
    pmax = fmaxf(pmax, __shfl_xor(pmax, 16));
    pmax = fmaxf(pmax, __shfl_xor(pmax, 32));
    if (!__all(pmax - m_ <= 8.0f)) {      // defer-max: skip rescale if growth small
      float mn = fmaxf(m_, pmax);
      float corr = EXP2F(m_ - mn);        // exp2(-inf) = 0 handles t=0
      m_ = mn;
      #pragma unroll
      for (int dt = 0; dt < 4; ++dt)
        #pragma unroll
        for (int r = 0; r < 4; ++r) o[dt][r] *= corr;
      #pragma unroll
      for (int r = 0; r < 4; ++r) o_l[r] *= corr;
    }

    // fused exp -> pack -> P ds_write per jt (denominator via ones-MFMA)
    #pragma unroll
    for (int jt = 0; jt < 4; ++jt) {
      short4v pv;
      pv[0] = f2b(EXP2F(s[jt][0] - m_));
      pv[1] = f2b(EXP2F(s[jt][1] - m_));
      pv[2] = f2b(EXP2F(s[jt][2] - m_));
      pv[3] = f2b(EXP2F(s[jt][3] - m_));
      *(short4v*)&p_lds[pw[jt]] = pv;
    }

    // O^T += V^T P^T ; o_l += 1^T P^T (row-sum of P via MFMA)
    #pragma unroll
    for (int kk = 0; kk < 2; ++kk) {
      short8 pa = *(const short8*)&p_lds[pr[kk]];
      o_l = MFMA16(ones, pa, o_l);
      #pragma unroll
      for (int dt = 0; dt < 4; ++dt) {
        short8 vb = *(const short8*)&v_lds[cur][(dt * 16 + lr) * 64 +
                                               (((kk * 4 + lg) ^ rm) * 8)];
        o[dt] = MFMA16(vb, pa, o[dt]);
      }
    }

    // counted wait: only require tile t+1 landed; t+2's 2 loads stay in flight
    if (t < 31) {
      if (t < 30) asm volatile("s_waitcnt vmcnt(2)" ::: "memory");
      else        asm volatile("s_waitcnt vmcnt(0)" ::: "memory");
      __syncthreads();
    }
    cur = (cur == 2) ? 0 : cur + 1;
    nx2 = (nx2 == 2) ? 0 : nx2 + 1;
  }

  // epilogue: out layout [b][n][h*64+d] bf16; n = q0+lr, packed 8B stores
  const int bb = bh >> 4, h = bh & 15;
  const float inv_l = __frcp_rn(o_l[0]);   // all 4 regs equal (ones rows)
  #pragma unroll
  for (int dt = 0; dt < 4; ++dt) {
    short4v ov;
    #pragma unroll
    for (int r = 0; r < 4; ++r) ov[r] = f2b(o[dt][r] * inv_l);
    *(short4v*)&aob[(size_t)(bb * 2048 + q0 + lr) * 1024 + h * 64 + dt * 16 + lg * 4] = ov;
  }
}

// ---------------- GEMM2: out = aob @ wprojT^T + b_proj (fp32 out) ----------------
// 64x128 tile, BK=64, 1D grid 512 (2 blocks/CU), XCD swizzle, T2 LDS swizzle.
__global__ __launch_bounds__(256, 2) void gemm_proj(const short* __restrict__ aob,
                                                    const short* __restrict__ wT,
                                                    const float* __restrict__ bias,
                                                    float* __restrict__ out) {
  __shared__ short lds_a[64 * 64];
  __shared__ short lds_b[128 * 64];
  const int tid = threadIdx.x, wid = tid >> 6, lane = tid & 63;
  const int lg = lane >> 4, lr = lane & 15;
  const int lin = blockIdx.x;
  const int swz = (lin & 7) * 64 + (lin >> 3);
  const int m0 = (swz & 63) * 64, n0 = (swz >> 6) * 128;  // same-B-panel per XCD
  const int mw = wid >> 1, nw = wid & 1;
  const int K = 1024;
  const int sm = lr & 7;

  f32x4 acc[2][4];
  #pragma unroll
  for (int i = 0; i < 2; ++i)
    #pragma unroll
    for (int j = 0; j < 4; ++j) acc[i][j] = (f32x4)0.0f;

  for (int k0 = 0; k0 < K; k0 += 64) {
    #pragma unroll
    for (int it = 0; it < 2; ++it) {                        // A: 64 x 64
      int chunk = it * 256 + tid;
      int row = chunk >> 3, kc = ((chunk & 7) ^ (row & 7)) * 8;
      async_lds16(aob + (size_t)(m0 + row) * K + k0 + kc, lds_a + chunk * 8);
    }
    #pragma unroll
    for (int it = 0; it < 4; ++it) {                        // B: 128 x 64
      int chunk = it * 256 + tid;
      int row = chunk >> 3, kc = ((chunk & 7) ^ (row & 7)) * 8;
      async_lds16(wT + (size_t)(n0 + row) * K + k0 + kc, lds_b + chunk * 8);
    }
    __syncthreads();
    #pragma unroll
    for (int kk = 0; kk < 2; ++kk) {
      short8 af[2], bfr[4];
      #pragma unroll
      for (int i = 0; i < 2; ++i)
        af[i] = *(const short8*)&lds_a[(mw * 32 + i * 16 + lr) * 64 +
                                       (((kk * 4 + lg) ^ sm) * 8)];
      #pragma unroll
      for (int j = 0; j < 4; ++j)
        bfr[j] = *(const short8*)&lds_b[(nw * 64 + j * 16 + lr) * 64 +
                                        (((kk * 4 + lg) ^ sm) * 8)];
      #pragma unroll
      for (int i = 0; i < 2; ++i)
        #pragma unroll
        for (int j = 0; j < 4; ++j) acc[i][j] = MFMA16(af[i], bfr[j], acc[i][j]);
    }
    __syncthreads();
  }

  #pragma unroll
  for (int i = 0; i < 2; ++i) {
    int gm = m0 + mw * 32 + i * 16 + lg * 4;
    #pragma unroll
    for (int j = 0; j < 4; ++j) {
      int gc = n0 + nw * 64 + j * 16 + lr;
      float bv = bias[gc];
      #pragma unroll
      for (int r = 0; r < 4; ++r)
        out[(size_t)(gm + r) * 1024 + gc] = acc[i][j][r] + bv;
    }
  }
}

// ---------------- launcher ----------------
extern "C" void kernel_launch(void* const* d_in, const int* in_sizes, int n_in,
                              void* d_out, int out_size, void* d_ws, size_t ws_size,
                              hipStream_t stream) {
  const float* x     = (const float*)d_in[0];  // [2,2048,1024]
  const float* wqkv  = (const float*)d_in[1];  // [1024,3072]
  const float* bqkv  = (const float*)d_in[2];  // [3072]
  const float* wproj = (const float*)d_in[3];  // [1024,1024]
  const float* bproj = (const float*)d_in[4];  // [1024]
  float* out = (float*)d_out;

  char* ws = (char*)d_ws;
  short* xb     = (short*)ws; ws += (size_t)4096 * 1024 * 2;  // 8 MB
  short* wqkvT  = (short*)ws; ws += (size_t)3072 * 1024 * 2;  // 6 MB
  short* wprojT = (short*)ws; ws += (size_t)1024 * 1024 * 2;  // 2 MB
  short* Qb     = (short*)ws; ws += (size_t)32 * 2048 * 64 * 2;  // 8 MB
  short* Kb     = (short*)ws; ws += (size_t)32 * 2048 * 64 * 2;  // 8 MB
  short* Vt     = (short*)ws; ws += (size_t)32 * 64 * 2048 * 2;  // 8 MB
  short* aob    = (short*)ws; ws += (size_t)4096 * 1024 * 2;     // 8 MB
  // total 48 MB workspace

  cast_f32_bf16<<<1024, 256, 0, stream>>>(x, xb, 4096 * 1024 / 4);
  transpose_cast_w<<<1024, 256, 0, stream>>>(wqkv, wqkvT, wproj, wprojT);
  gemm_qkv<<<768, 256, 0, stream>>>(xb, wqkvT, bqkv, Qb, Kb, Vt);
  attn_fwd<<<512, 512, 0, stream>>>(Qb, Kb, Vt, aob);
  gemm_proj<<<512, 256, 0, stream>>>(aob, wprojT, bproj, out);
}

// Round 15
// 183.051 us; speedup vs baseline: 1.0543x; 1.0543x over previous
//
#include <hip/hip_runtime.h>
#include <hip/hip_bf16.h>
#include <cstdint>
#include <cstddef>

// MHA fused pipeline, bf16 MFMA everywhere, fp32 accumulate.
// B=2 N=2048 E=1024 H=16 D=64; M = B*N = 4096; BH = 32.
// R1: attn LDS XOR-swizzle (verified: SQ_LDS_BANK_CONFLICT=0).
// R2: swapped QK^T -> lane-local softmax (122 -> 76 us).
// R4/R5: K/V dbuf prefetch, exp2 softmax, defer-max, XCD swizzles (-> 67 us).
// R6: GEMMs BK=64 + T2 swizzle; attn setprio REGRESSED (-> 70.6).
// R7/R8: revert setprio, cvt_pk casts, tree reductions (-> 63.3 us).
// R9/R10: ones-MFMA denominator + launch diet (attn 64.1; total 192).
// R11: K16 in-register PV REGRESSED (68.4). R12: 3-buf counted vmcnt (-> 59.7).
// R13: KVBLK=128 REGRESSED (62.7) — but conflict-confounded (V layout 3x).
// R14: revert attn to R12 (60.0); merged weight transposes.
// R15: clean barrier-halving test — 4x verified 64-tile buffers, unroll-by-2:
//      16 barriers (was 32), shuffles halved, SAME K/V/P layouts (conflicts
//      must stay 2.1M). Drain window 2 tiles >> HBM latency. Also fold x-cast
//      into the preprocessing kernel (one fewer launch).

typedef __attribute__((ext_vector_type(8))) short short8;   // 8 bf16 (4 VGPR)
typedef __attribute__((ext_vector_type(4))) short short4v;
typedef __attribute__((ext_vector_type(4))) float f32x4;

#define MFMA16(a, b, c) __builtin_amdgcn_mfma_f32_16x16x32_bf16((a), (b), (c), 0, 0, 0)
#define EXP2F(x) __builtin_amdgcn_exp2f(x)

__device__ __forceinline__ float b2f(short s) {
  union { unsigned u; float f; } x; x.u = ((unsigned)(unsigned short)s) << 16; return x.f;
}
__device__ __forceinline__ short f2b(float f) {  // native RNE cast (cvt_pk-fusable)
  union { __hip_bfloat16 h; short s; } u; u.h = __float2bfloat16(f); return u.s;
}
__device__ __forceinline__ void async_lds16(const void* g, void* l) {
  __builtin_amdgcn_global_load_lds(
      (const __attribute__((address_space(1))) void*)g,
      (__attribute__((address_space(3))) void*)l, 16, 0, 0);
}

// ---- merged preprocessing: weight transposes + x cast, one launch ----
// blocks 0..767: wqkv transpose (C=3072); 768..1023: wproj (C=1024);
// blocks 1024..1535: cast x f32->bf16 (grid-stride over 1M float4).
__global__ __launch_bounds__(256) void preproc(const float* __restrict__ wqkv,
                                               short* __restrict__ wqkvT,
                                               const float* __restrict__ wproj,
                                               short* __restrict__ wprojT,
                                               const float* __restrict__ x,
                                               short* __restrict__ xb) {
  int b = blockIdx.x;
  if (b >= 1024) {                       // cast x
    int n4 = 4096 * 1024 / 4;
    for (int idx = (b - 1024) * 256 + threadIdx.x; idx < n4; idx += 512 * 256) {
      f32x4 v = ((const f32x4*)x)[idx];
      short4v o;
      #pragma unroll
      for (int e = 0; e < 4; ++e) o[e] = f2b(v[e]);
      ((short4v*)xb)[idx] = o;
    }
    return;
  }
  __shared__ float tile[64][65];
  const float* in;
  short* out;
  int C, bx, by;
  if (b < 768) { in = wqkv;  out = wqkvT;  C = 3072; bx = b % 48; by = b / 48; }
  else { b -= 768; in = wproj; out = wprojT; C = 1024; bx = b % 16; by = b / 16; }
  const int R = 1024;
  int c0 = bx * 64, r0 = by * 64;
  int tx = threadIdx.x & 63, ty = threadIdx.x >> 6;  // 64 x 4
  #pragma unroll
  for (int i = ty; i < 64; i += 4)
    tile[i][tx] = in[(size_t)(r0 + i) * C + c0 + tx];
  __syncthreads();
  #pragma unroll
  for (int i = ty; i < 64; i += 4)
    out[(size_t)(c0 + i) * R + r0 + tx] = f2b(tile[tx][i]);
}

// ---------------- GEMM1: qkv = xb @ wqkvT^T + bias, scatter to Q/K/Vt ----------------
// 128x128 tile, BK=64, 1D grid 768, chunked XCD swizzle. LDS [128][64] with
// T2 XOR swizzle: 16B-block idx ^= (row&7); linear LDS dest + pre-swz source.
__global__ __launch_bounds__(256, 3) void gemm_qkv(const short* __restrict__ xb,
                                                   const short* __restrict__ wT,
                                                   const float* __restrict__ bias,
                                                   short* __restrict__ Qb,
                                                   short* __restrict__ Kb,
                                                   short* __restrict__ Vt) {
  __shared__ short lds_a[128 * 64];
  __shared__ short lds_b[128 * 64];
  const int tid = threadIdx.x, wid = tid >> 6, lane = tid & 63;
  const int lg = lane >> 4, lr = lane & 15;
  const int lin = blockIdx.x;
  const int swz = (lin & 7) * 96 + (lin >> 3);   // XCD k owns swz [k*96, (k+1)*96)
  const int m0 = (swz & 31) * 128, n0 = (swz >> 5) * 128;
  const int wr = wid >> 1, wc = wid & 1;
  const int K = 1024;
  const int sm = lr & 7;                         // read-side swizzle mask

  f32x4 acc[4][4];
  #pragma unroll
  for (int i = 0; i < 4; ++i)
    #pragma unroll
    for (int j = 0; j < 4; ++j) acc[i][j] = (f32x4)0.0f;

  for (int k0 = 0; k0 < K; k0 += 64) {
    #pragma unroll
    for (int it = 0; it < 4; ++it) {
      int chunk = it * 256 + tid;
      int row = chunk >> 3, kc = ((chunk & 7) ^ (row & 7)) * 8;  // pre-swz source
      async_lds16(xb + (size_t)(m0 + row) * K + k0 + kc, lds_a + chunk * 8);
      async_lds16(wT + (size_t)(n0 + row) * K + k0 + kc, lds_b + chunk * 8);
    }
    __syncthreads();
    #pragma unroll
    for (int kk = 0; kk < 2; ++kk) {
      short8 af[4], bfr[4];
      #pragma unroll
      for (int i = 0; i < 4; ++i)
        af[i] = *(const short8*)&lds_a[(wr * 64 + i * 16 + lr) * 64 +
                                       (((kk * 4 + lg) ^ sm) * 8)];
      #pragma unroll
      for (int j = 0; j < 4; ++j)
        bfr[j] = *(const short8*)&lds_b[(wc * 64 + j * 16 + lr) * 64 +
                                        (((kk * 4 + lg) ^ sm) * 8)];
      #pragma unroll
      for (int i = 0; i < 4; ++i)
        #pragma unroll
        for (int j = 0; j < 4; ++j) acc[i][j] = MFMA16(af[i], bfr[j], acc[i][j]);
    }
    __syncthreads();
  }

  // epilogue: C/D layout col = lane&15, row = (lane>>4)*4 + reg
  #pragma unroll
  for (int i = 0; i < 4; ++i) {
    int gm = m0 + wr * 64 + i * 16 + lg * 4;  // rows gm..gm+3 (same b: gm%4==0)
    int bb = gm >> 11, n = gm & 2047;
    #pragma unroll
    for (int j = 0; j < 4; ++j) {
      int gc = n0 + wc * 64 + j * 16 + lr;
      float bv = bias[gc];
      int which = gc >> 10;            // uniform per block (n0 % 128 == 0)
      int h = (gc >> 6) & 15;
      int dd = gc & 63;
      size_t qkbase = ((size_t)((bb * 16 + h) * 2048 + n)) * 64 + dd;
      if (which == 2) {                // Vt: r contiguous along n -> pack 8B
        size_t vtbase = ((size_t)((bb * 16 + h) * 64 + dd)) * 2048 + n;
        short4v pv;
        #pragma unroll
        for (int r = 0; r < 4; ++r) pv[r] = f2b(acc[i][j][r] + bv);
        *(short4v*)&Vt[vtbase] = pv;
      } else {
        short* dst = (which == 0) ? Qb : Kb;
        #pragma unroll
        for (int r = 0; r < 4; ++r)
          dst[qkbase + (size_t)r * 64] = f2b(acc[i][j][r] + bv);
      }
    }
  }
}

// ---------------- flash attention (4-buffer, pair-unrolled) ----------------
// 1D grid 512, 512 threads / 8 waves; wave owns 16 q-rows (q = q0+lr).
// 32 KV tiles of 64, FOUR buffers (verified [64][64] layouts), unroll-by-2:
//   prologue: stage tiles 0,1 -> bufs 0,1; vmcnt(0); barrier.
//   pair tp:  stage tiles t0+2,t0+3 -> bufs (t0+2)&3,(t0+3)&3;
//             compute t0,t0+1 (s[8], ONE softmax over 128 cols);
//             vmcnt(0)+barrier (drain window = 2 tiles >> HBM latency).
// 16 barriers instead of 32; shuffle pairs halved. Layouts byte-identical to
// R12 => SQ_LDS_BANK_CONFLICT must stay ~2.1M (checks the clean hypothesis).
__global__ __launch_bounds__(512) void attn_fwd(const short* __restrict__ Qb,
                                                const short* __restrict__ Kb,
                                                const short* __restrict__ Vt,
                                                short* __restrict__ aob) {
  __shared__ short k_lds[4][64 * 64];
  __shared__ short v_lds[4][64 * 64];
  __shared__ short p_lds[8 * 16 * 64];
  const int tid = threadIdx.x, wid = tid >> 6, lane = tid & 63;
  const int lg = lane >> 4, lr = lane & 15;
  const int lin = blockIdx.x;
  const int swz = (lin & 7) * 64 + (lin >> 3);
  const int qt = swz & 15, bh = swz >> 4;   // XCD k owns bh [k*4, k*4+4)
  const int q0 = qt * 128 + wid * 16;
  const short* Qbh = Qb + (size_t)bh * 2048 * 64;
  const short* Kbh = Kb + (size_t)bh * 2048 * 64;
  const short* Vbh = Vt + (size_t)bh * 64 * 2048;
  const int rm = (lr >> 1) & 7;   // read-side swizzle mask (rows indexed by lr)

  // stage one KV tile (linear LDS dest + pre-swizzled global source)
  const int srow = tid >> 3;
  const int ssrc = ((tid & 7) ^ ((srow >> 1) & 7)) * 8;
  #define STAGE64(buf, kv0)                                                   \
    async_lds16(Kbh + (size_t)((kv0) + srow) * 64 + ssrc, &k_lds[buf][tid * 8]); \
    async_lds16(Vbh + (size_t)srow * 2048 + (kv0) + ssrc, &v_lds[buf][tid * 8]);

  // loop-invariant p_lds write/read offsets
  int pw[4], pr[2];
  #pragma unroll
  for (int jt = 0; jt < 4; ++jt)
    pw[jt] = wid * 1024 + lr * 64 + (((jt * 2 + (lg >> 1)) ^ rm) * 8) + (lg & 1) * 4;
  #pragma unroll
  for (int kk = 0; kk < 2; ++kk)
    pr[kk] = wid * 1024 + lr * 64 + (((kk * 4 + lg) ^ rm) * 8);

  // all-ones bf16 fragment for the denominator MFMA
  short8 ones;
  #pragma unroll
  for (int e = 0; e < 8; ++e) ones[e] = (short)0x3F80;

  // Q fragments hoisted; fold scale 0.125 * log2(e) (exp2-domain scores)
  short8 qf[2];
  #pragma unroll
  for (int kk = 0; kk < 2; ++kk) {
    qf[kk] = *(const short8*)(Qbh + (size_t)(q0 + lr) * 64 + kk * 32 + lg * 8);
    #pragma unroll
    for (int e = 0; e < 8; ++e) qf[kk][e] = f2b(b2f(qf[kk][e]) * 0.1803368801f);
  }

  f32x4 o[4], o_l;
  #pragma unroll
  for (int dt = 0; dt < 4; ++dt) o[dt] = (f32x4)0.0f;
  o_l = (f32x4)0.0f;
  float m_ = -__builtin_inff();

  // prologue: stage tiles 0,1 into bufs 0,1
  STAGE64(0, 0)
  STAGE64(1, 64)
  asm volatile("s_waitcnt vmcnt(0)" ::: "memory");
  __syncthreads();

  for (int tp = 0; tp < 16; ++tp) {
    const int t0 = tp * 2;
    const int b0 = (tp & 1) * 2, b1 = b0 + 1;   // tiles t0 -> b0, t0+1 -> b1
    // issue tiles t0+2, t0+3 into the pair of slots freed at tp-1
    if (tp < 15) {
      const int c0 = (b0 + 2) & 3, c1 = (b1 + 2) & 3;
      STAGE64(c0, (t0 + 2) * 64)
      STAGE64(c1, (t0 + 3) * 64)
    }

    // S^T over both tiles: s[c*4+jt][r] = S[q=lr][k = c*64 + jt*16+lg*4+r]
    f32x4 s[8];
    #pragma unroll
    for (int j = 0; j < 8; ++j) s[j] = (f32x4)0.0f;
    #pragma unroll
    for (int c = 0; c < 2; ++c) {
      const short* kb = k_lds[c ? b1 : b0];
      #pragma unroll
      for (int jt = 0; jt < 4; ++jt)
        #pragma unroll
        for (int kk = 0; kk < 2; ++kk) {
          short8 kf = *(const short8*)&kb[(jt * 16 + lr) * 64 +
                                          (((kk * 4 + lg) ^ rm) * 8)];
          s[c * 4 + jt] = MFMA16(kf, qf[kk], s[c * 4 + jt]);
        }
    }

    // ONE softmax pass over 128 cols: pmax tree + shuffle pair
    float mj[8];
    #pragma unroll
    for (int j = 0; j < 8; ++j)
      mj[j] = fmaxf(fmaxf(s[j][0], s[j][1]), fmaxf(s[j][2], s[j][3]));
    float pmax = fmaxf(fmaxf(fmaxf(mj[0], mj[1]), fmaxf(mj[2], mj[3])),
                       fmaxf(fmaxf(mj[4], mj[5]), fmaxf(mj[6], mj[7])));
    pmax = fmaxf(pmax, __shfl_xor(pmax, 16));
    pmax = fmaxf(pmax, __shfl_xor(pmax, 32));
    if (!__all(pmax - m_ <= 8.0f)) {      // defer-max: skip rescale if growth small
      float mn = fmaxf(m_, pmax);
      float corr = EXP2F(m_ - mn);        // exp2(-inf) = 0 handles t=0
      m_ = mn;
      #pragma unroll
      for (int dt = 0; dt < 4; ++dt)
        #pragma unroll
        for (int r = 0; r < 4; ++r) o[dt][r] *= corr;
      #pragma unroll
      for (int r = 0; r < 4; ++r) o_l[r] *= corr;
    }

    // PV per 64-chunk (p_lds reused; per-wave private, lgkm-ordered)
    #pragma unroll
    for (int c = 0; c < 2; ++c) {
      #pragma unroll
      for (int jt = 0; jt < 4; ++jt) {
        f32x4 sv = s[c * 4 + jt];
        short4v pv;
        pv[0] = f2b(EXP2F(sv[0] - m_));
        pv[1] = f2b(EXP2F(sv[1] - m_));
        pv[2] = f2b(EXP2F(sv[2] - m_));
        pv[3] = f2b(EXP2F(sv[3] - m_));
        *(short4v*)&p_lds[pw[jt]] = pv;
      }
      const short* vb0 = v_lds[c ? b1 : b0];
      #pragma unroll
      for (int kk = 0; kk < 2; ++kk) {
        short8 pa = *(const short8*)&p_lds[pr[kk]];
        o_l = MFMA16(ones, pa, o_l);
        #pragma unroll
        for (int dt = 0; dt < 4; ++dt) {
          short8 vb = *(const short8*)&vb0[(dt * 16 + lr) * 64 +
                                           (((kk * 4 + lg) ^ rm) * 8)];
          o[dt] = MFMA16(vb, pa, o[dt]);
        }
      }
    }

    // drain: the 4 staging loads had the full 2-tile compute window to land
    if (tp < 15) {
      asm volatile("s_waitcnt vmcnt(0)" ::: "memory");
      __syncthreads();
    }
  }
  #undef STAGE64

  // epilogue: out layout [b][n][h*64+d] bf16; n = q0+lr, packed 8B stores
  const int bb = bh >> 4, h = bh & 15;
  const float inv_l = __frcp_rn(o_l[0]);   // all 4 regs equal (ones rows)
  #pragma unroll
  for (int dt = 0; dt < 4; ++dt) {
    short4v ov;
    #pragma unroll
    for (int r = 0; r < 4; ++r) ov[r] = f2b(o[dt][r] * inv_l);
    *(short4v*)&aob[(size_t)(bb * 2048 + q0 + lr) * 1024 + h * 64 + dt * 16 + lg * 4] = ov;
  }
}

// ---------------- GEMM2: out = aob @ wprojT^T + b_proj (fp32 out) ----------------
// 64x128 tile, BK=64, 1D grid 512 (2 blocks/CU), XCD swizzle, T2 LDS swizzle.
__global__ __launch_bounds__(256, 2) void gemm_proj(const short* __restrict__ aob,
                                                    const short* __restrict__ wT,
                                                    const float* __restrict__ bias,
                                                    float* __restrict__ out) {
  __shared__ short lds_a[64 * 64];
  __shared__ short lds_b[128 * 64];
  const int tid = threadIdx.x, wid = tid >> 6, lane = tid & 63;
  const int lg = lane >> 4, lr = lane & 15;
  const int lin = blockIdx.x;
  const int swz = (lin & 7) * 64 + (lin >> 3);
  const int m0 = (swz & 63) * 64, n0 = (swz >> 6) * 128;  // same-B-panel per XCD
  const int mw = wid >> 1, nw = wid & 1;
  const int K = 1024;
  const int sm = lr & 7;

  f32x4 acc[2][4];
  #pragma unroll
  for (int i = 0; i < 2; ++i)
    #pragma unroll
    for (int j = 0; j < 4; ++j) acc[i][j] = (f32x4)0.0f;

  for (int k0 = 0; k0 < K; k0 += 64) {
    #pragma unroll
    for (int it = 0; it < 2; ++it) {                        // A: 64 x 64
      int chunk = it * 256 + tid;
      int row = chunk >> 3, kc = ((chunk & 7) ^ (row & 7)) * 8;
      async_lds16(aob + (size_t)(m0 + row) * K + k0 + kc, lds_a + chunk * 8);
    }
    #pragma unroll
    for (int it = 0; it < 4; ++it) {                        // B: 128 x 64
      int chunk = it * 256 + tid;
      int row = chunk >> 3, kc = ((chunk & 7) ^ (row & 7)) * 8;
      async_lds16(wT + (size_t)(n0 + row) * K + k0 + kc, lds_b + chunk * 8);
    }
    __syncthreads();
    #pragma unroll
    for (int kk = 0; kk < 2; ++kk) {
      short8 af[2], bfr[4];
      #pragma unroll
      for (int i = 0; i < 2; ++i)
        af[i] = *(const short8*)&lds_a[(mw * 32 + i * 16 + lr) * 64 +
                                       (((kk * 4 + lg) ^ sm) * 8)];
      #pragma unroll
      for (int j = 0; j < 4; ++j)
        bfr[j] = *(const short8*)&lds_b[(nw * 64 + j * 16 + lr) * 64 +
                                        (((kk * 4 + lg) ^ sm) * 8)];
      #pragma unroll
      for (int i = 0; i < 2; ++i)
        #pragma unroll
        for (int j = 0; j < 4; ++j) acc[i][j] = MFMA16(af[i], bfr[j], acc[i][j]);
    }
    __syncthreads();
  }

  #pragma unroll
  for (int i = 0; i < 2; ++i) {
    int gm = m0 + mw * 32 + i * 16 + lg * 4;
    #pragma unroll
    for (int j = 0; j < 4; ++j) {
      int gc = n0 + nw * 64 + j * 16 + lr;
      float bv = bias[gc];
      #pragma unroll
      for (int r = 0; r < 4; ++r)
        out[(size_t)(gm + r) * 1024 + gc] = acc[i][j][r] + bv;
    }
  }
}

// ---------------- launcher ----------------
extern "C" void kernel_launch(void* const* d_in, const int* in_sizes, int n_in,
                              void* d_out, int out_size, void* d_ws, size_t ws_size,
                              hipStream_t stream) {
  const float* x     = (const float*)d_in[0];  // [2,2048,1024]
  const float* wqkv  = (const float*)d_in[1];  // [1024,3072]
  const float* bqkv  = (const float*)d_in[2];  // [3072]
  const float* wproj = (const float*)d_in[3];  // [1024,1024]
  const float* bproj = (const float*)d_in[4];  // [1024]
  float* out = (float*)d_out;

  char* ws = (char*)d_ws;
  short* xb     = (short*)ws; ws += (size_t)4096 * 1024 * 2;  // 8 MB
  short* wqkvT  = (short*)ws; ws += (size_t)3072 * 1024 * 2;  // 6 MB
  short* wprojT = (short*)ws; ws += (size_t)1024 * 1024 * 2;  // 2 MB
  short* Qb     = (short*)ws; ws += (size_t)32 * 2048 * 64 * 2;  // 8 MB
  short* Kb     = (short*)ws; ws += (size_t)32 * 2048 * 64 * 2;  // 8 MB
  short* Vt     = (short*)ws; ws += (size_t)32 * 64 * 2048 * 2;  // 8 MB
  short* aob    = (short*)ws; ws += (size_t)4096 * 1024 * 2;     // 8 MB
  // total 48 MB workspace

  preproc<<<1536, 256, 0, stream>>>(wqkv, wqkvT, wproj, wprojT, x, xb);
  gemm_qkv<<<768, 256, 0, stream>>>(xb, wqkvT, bqkv, Qb, Kb, Vt);
  attn_fwd<<<512, 512, 0, stream>>>(Qb, Kb, Vt, aob);
  gemm_proj<<<512, 256, 0, stream>>>(aob, wprojT, bproj, out);
}